// Round 3
// baseline (74.257 us; speedup 1.0000x reference)
//
#include <hip/hip_runtime.h>
#include <hip/hip_bf16.h>

#define B_ 32
#define L_ 2048
#define E_ 256
#define H_ 256
#define MAXSTEP 20

typedef __attribute__((ext_vector_type(4))) float f32x4;
typedef __attribute__((ext_vector_type(8))) short bf16x8;
using bf16 = __hip_bfloat16;

__device__ inline short cvt1(float x) {
    bf16 b = __float2bfloat16(x);
    return *reinterpret_cast<short*>(&b);
}

// Transpose + convert: cnn fp32 [s][e][h] -> wt bf16 [s][h][e] (K-contiguous B operand).
__global__ void transpose_w_kernel(const float* __restrict__ cnn, short* __restrict__ wt) {
    __shared__ short tile[32][33];
    const int s  = blockIdx.z;
    const int e0 = blockIdx.y * 32;
    const int h0 = blockIdx.x * 32;
    const int tx = threadIdx.x;
    const int ty = threadIdx.y;
    const float* src = cnn + ((size_t)s * E_ + e0) * H_ + h0;
#pragma unroll
    for (int i = ty; i < 32; i += 8)
        tile[i][tx] = cvt1(src[(size_t)i * H_ + tx]);
    __syncthreads();
    short* dst = wt + ((size_t)s * H_ + h0) * E_ + e0;
#pragma unroll
    for (int i = ty; i < 32; i += 8)
        dst[(size_t)i * E_ + tx] = tile[tx][i];
}

// One block per position l. 4 waves; wave w: rows b=0..31, cols h in [w*64, w*64+64).
// Deep-ILP version: all A loads issued up front (32 x dwordx4 in flight),
// B-frag loads double-buffered one k-step ahead.
template <bool TRANS>
__global__ __launch_bounds__(256, 2) void vaw_mfma_kernel(
        const float* __restrict__ A, const void* __restrict__ W, float* __restrict__ out) {
    const int l    = blockIdx.x;
    const int s    = l % MAXSTEP;
    const int wv   = threadIdx.x >> 6;
    const int lane = threadIdx.x & 63;
    const int r    = lane & 15;
    const int g    = lane >> 4;
    const int nbase = wv * 64;

    f32x4 acc[2][4] = {};

    const float* aptr0 = A + ((size_t)r * L_ + l) * E_ + g * 8;
    const float* aptr1 = A + ((size_t)(r + 16) * L_ + l) * E_ + g * 8;

    // ---- Phase 1: issue ALL A loads (2 rows x 8 ksteps x 2 dwordx4 = 128 VGPR in flight)
    f32x4 a0reg[8][2], a1reg[8][2];
#pragma unroll
    for (int kk = 0; kk < 8; ++kk) {
        a0reg[kk][0] = *(const f32x4*)(aptr0 + kk * 32);
        a0reg[kk][1] = *(const f32x4*)(aptr0 + kk * 32 + 4);
        a1reg[kk][0] = *(const f32x4*)(aptr1 + kk * 32);
        a1reg[kk][1] = *(const f32x4*)(aptr1 + kk * 32 + 4);
    }

    if constexpr (TRANS) {
        const short* wtb = (const short*)W + ((size_t)s * H_ + nbase + r) * E_ + g * 8;
        // ---- Phase 2: B double-buffered (L2-resident), convert + MFMA per kstep
        bf16x8 bbuf[2][4];
#pragma unroll
        for (int nf = 0; nf < 4; ++nf)
            bbuf[0][nf] = *(const bf16x8*)(wtb + (size_t)nf * 16 * E_);
#pragma unroll
        for (int kk = 0; kk < 8; ++kk) {
            if (kk < 7) {
#pragma unroll
                for (int nf = 0; nf < 4; ++nf)
                    bbuf[(kk + 1) & 1][nf] =
                        *(const bf16x8*)(wtb + (size_t)nf * 16 * E_ + (kk + 1) * 32);
            }
            bf16x8 a0, a1;
#pragma unroll
            for (int j = 0; j < 4; ++j) {
                a0[j]     = cvt1(a0reg[kk][0][j]);
                a0[j + 4] = cvt1(a0reg[kk][1][j]);
                a1[j]     = cvt1(a1reg[kk][0][j]);
                a1[j + 4] = cvt1(a1reg[kk][1][j]);
            }
#pragma unroll
            for (int nf = 0; nf < 4; ++nf) {
                acc[0][nf] = __builtin_amdgcn_mfma_f32_16x16x32_bf16(a0, bbuf[kk & 1][nf], acc[0][nf], 0, 0, 0);
                acc[1][nf] = __builtin_amdgcn_mfma_f32_16x16x32_bf16(a1, bbuf[kk & 1][nf], acc[1][nf], 0, 0, 0);
            }
        }
    } else {
        const float* Wf = (const float*)W + (size_t)s * E_ * H_;
#pragma unroll
        for (int kk = 0; kk < 8; ++kk) {
            const int k0 = kk * 32;
            bf16x8 a0, a1;
#pragma unroll
            for (int j = 0; j < 4; ++j) {
                a0[j]     = cvt1(a0reg[kk][0][j]);
                a0[j + 4] = cvt1(a0reg[kk][1][j]);
                a1[j]     = cvt1(a1reg[kk][0][j]);
                a1[j + 4] = cvt1(a1reg[kk][1][j]);
            }
            bf16x8 b0, b1, b2, b3;
#pragma unroll
            for (int j = 0; j < 8; ++j) {
                const size_t krow = (size_t)(k0 + g * 8 + j) * H_;
                b0[j] = cvt1(Wf[krow + nbase +  0 + r]);
                b1[j] = cvt1(Wf[krow + nbase + 16 + r]);
                b2[j] = cvt1(Wf[krow + nbase + 32 + r]);
                b3[j] = cvt1(Wf[krow + nbase + 48 + r]);
            }
            acc[0][0] = __builtin_amdgcn_mfma_f32_16x16x32_bf16(a0, b0, acc[0][0], 0, 0, 0);
            acc[0][1] = __builtin_amdgcn_mfma_f32_16x16x32_bf16(a0, b1, acc[0][1], 0, 0, 0);
            acc[0][2] = __builtin_amdgcn_mfma_f32_16x16x32_bf16(a0, b2, acc[0][2], 0, 0, 0);
            acc[0][3] = __builtin_amdgcn_mfma_f32_16x16x32_bf16(a0, b3, acc[0][3], 0, 0, 0);
            acc[1][0] = __builtin_amdgcn_mfma_f32_16x16x32_bf16(a1, b0, acc[1][0], 0, 0, 0);
            acc[1][1] = __builtin_amdgcn_mfma_f32_16x16x32_bf16(a1, b1, acc[1][1], 0, 0, 0);
            acc[1][2] = __builtin_amdgcn_mfma_f32_16x16x32_bf16(a1, b2, acc[1][2], 0, 0, 0);
            acc[1][3] = __builtin_amdgcn_mfma_f32_16x16x32_bf16(a1, b3, acc[1][3], 0, 0, 0);
        }
    }

    const int row0 = g * 4;
#pragma unroll
    for (int mf = 0; mf < 2; ++mf) {
#pragma unroll
        for (int nf = 0; nf < 4; ++nf) {
            const int h = nbase + nf * 16 + r;
#pragma unroll
            for (int i = 0; i < 4; ++i) {
                const int bb = mf * 16 + row0 + i;
                out[((size_t)bb * L_ + l) * H_ + h] = acc[mf][nf][i];
            }
        }
    }
    if (l == L_ - 1) {
        float* out2 = out + (size_t)B_ * L_ * H_;
#pragma unroll
        for (int mf = 0; mf < 2; ++mf)
#pragma unroll
            for (int nf = 0; nf < 4; ++nf) {
                const int h = nbase + nf * 16 + r;
#pragma unroll
                for (int i = 0; i < 4; ++i) {
                    const int bb = mf * 16 + row0 + i;
                    out2[(size_t)bb * H_ + h] = acc[mf][nf][i];
                }
            }
    }
}

extern "C" void kernel_launch(void* const* d_in, const int* in_sizes, int n_in,
                              void* d_out, int out_size, void* d_ws, size_t ws_size,
                              hipStream_t stream) {
    const float* word_rep = (const float*)d_in[0];
    const float* cnn      = (const float*)d_in[1];
    float* out = (float*)d_out;

    const size_t wt_bytes = (size_t)MAXSTEP * E_ * H_ * sizeof(short);
    if (ws_size >= wt_bytes) {
        short* wt = (short*)d_ws;
        transpose_w_kernel<<<dim3(8, 8, 20), dim3(32, 8), 0, stream>>>(cnn, wt);
        vaw_mfma_kernel<true><<<dim3(L_), dim3(256), 0, stream>>>(word_rep, wt, out);
    } else {
        vaw_mfma_kernel<false><<<dim3(L_), dim3(256), 0, stream>>>(word_rep, cnn, out);
    }
}

// Round 4
// 60.057 us; speedup vs baseline: 1.2364x; 1.2364x over previous
//
#include <hip/hip_runtime.h>
#include <hip/hip_bf16.h>

#define B_ 32
#define L_ 2048
#define E_ 256
#define H_ 256
#define MAXSTEP 20

typedef __attribute__((ext_vector_type(4))) float f32x4;
typedef __attribute__((ext_vector_type(8))) short bf16x8;
using bf16 = __hip_bfloat16;

__device__ inline short cvt1(float x) {
    bf16 b = __float2bfloat16(x);
    return *reinterpret_cast<short*>(&b);
}

// Transpose + convert: cnn fp32 [s][e][h] -> wt bf16 [s][h][e] (K-contiguous B operand).
__global__ void transpose_w_kernel(const float* __restrict__ cnn, short* __restrict__ wt) {
    __shared__ short tile[32][33];
    const int s  = blockIdx.z;
    const int e0 = blockIdx.y * 32;
    const int h0 = blockIdx.x * 32;
    const int tx = threadIdx.x;
    const int ty = threadIdx.y;
    const float* src = cnn + ((size_t)s * E_ + e0) * H_ + h0;
#pragma unroll
    for (int i = ty; i < 32; i += 8)
        tile[i][tx] = cvt1(src[(size_t)i * H_ + tx]);
    __syncthreads();
    short* dst = wt + ((size_t)s * H_ + h0) * E_ + e0;
#pragma unroll
    for (int i = ty; i < 32; i += 8)
        dst[(size_t)i * E_ + tx] = tile[tx][i];
}

// One block per position l. A-tile (32x256 fp32, 32 KB) async-staged to LDS via
// global_load_lds (bytes in flight without VGPRs); XOR-swizzled on the GLOBAL
// source side (LDS dest must stay linear), same XOR on the ds_read side.
// 4 waves; wave w: rows b=0..31, cols h in [w*64, w*64+64).
template <bool TRANS>
__global__ __launch_bounds__(256) void vaw_mfma_kernel(
        const float* __restrict__ A, const void* __restrict__ W, float* __restrict__ out) {
    __shared__ __align__(16) float aLds[B_ * E_];   // 32 KB

    const int l    = blockIdx.x;
    const int s    = l % MAXSTEP;
    const int wv   = threadIdx.x >> 6;
    const int lane = threadIdx.x & 63;
    const int r    = lane & 15;
    const int g    = lane >> 4;
    const int nbase = wv * 64;

    // ---- Stage A: 8 rounds/wave, wave wv stages row b = t*4+wv (1 KB each).
    // Lane loads global 16B-chunk (lane ^ (b&7)); LDS dest linear (base + lane*16).
#pragma unroll
    for (int t = 0; t < 8; ++t) {
        const int b  = t * 4 + wv;
        const int cg = lane ^ (b & 7);
        const float* gp = A + ((size_t)b * L_ + l) * E_ + cg * 4;
        __builtin_amdgcn_global_load_lds(
            (const __attribute__((address_space(1))) void*)gp,
            (__attribute__((address_space(3))) void*)&aLds[b * 256],
            16, 0, 0);
    }

    f32x4 acc[2][4] = {};

    if constexpr (TRANS) {
        const short* wtb = (const short*)W + ((size_t)s * H_ + nbase + r) * E_ + g * 8;
        // Prefetch B buf0 (L2-resident) while A is in flight.
        bf16x8 bbuf[2][4];
#pragma unroll
        for (int nf = 0; nf < 4; ++nf)
            bbuf[0][nf] = *(const bf16x8*)(wtb + (size_t)nf * 16 * E_);

        asm volatile("s_waitcnt vmcnt(0)" ::: "memory");
        __syncthreads();

        const int key = r & 7;   // (r+16)&7 == r&7
#pragma unroll
        for (int kk = 0; kk < 8; ++kk) {
            if (kk < 7) {
#pragma unroll
                for (int nf = 0; nf < 4; ++nf)
                    bbuf[(kk + 1) & 1][nf] =
                        *(const bf16x8*)(wtb + (size_t)nf * 16 * E_ + (kk + 1) * 32);
            }
            const int c0 = kk * 8 + g * 2;
            f32x4 a0lo = *(const f32x4*)&aLds[r * 256 + ((c0 ^ key) << 2)];
            f32x4 a0hi = *(const f32x4*)&aLds[r * 256 + (((c0 + 1) ^ key) << 2)];
            f32x4 a1lo = *(const f32x4*)&aLds[(r + 16) * 256 + ((c0 ^ key) << 2)];
            f32x4 a1hi = *(const f32x4*)&aLds[(r + 16) * 256 + (((c0 + 1) ^ key) << 2)];
            bf16x8 a0, a1;
#pragma unroll
            for (int j = 0; j < 4; ++j) {
                a0[j]     = cvt1(a0lo[j]);
                a0[j + 4] = cvt1(a0hi[j]);
                a1[j]     = cvt1(a1lo[j]);
                a1[j + 4] = cvt1(a1hi[j]);
            }
#pragma unroll
            for (int nf = 0; nf < 4; ++nf) {
                acc[0][nf] = __builtin_amdgcn_mfma_f32_16x16x32_bf16(a0, bbuf[kk & 1][nf], acc[0][nf], 0, 0, 0);
                acc[1][nf] = __builtin_amdgcn_mfma_f32_16x16x32_bf16(a1, bbuf[kk & 1][nf], acc[1][nf], 0, 0, 0);
            }
        }
    } else {
        asm volatile("s_waitcnt vmcnt(0)" ::: "memory");
        __syncthreads();
        const float* Wf = (const float*)W + (size_t)s * E_ * H_;
        const int key = r & 7;
#pragma unroll 2
        for (int kk = 0; kk < 8; ++kk) {
            const int k0 = kk * 32;
            const int c0 = kk * 8 + g * 2;
            f32x4 a0lo = *(const f32x4*)&aLds[r * 256 + ((c0 ^ key) << 2)];
            f32x4 a0hi = *(const f32x4*)&aLds[r * 256 + (((c0 + 1) ^ key) << 2)];
            f32x4 a1lo = *(const f32x4*)&aLds[(r + 16) * 256 + ((c0 ^ key) << 2)];
            f32x4 a1hi = *(const f32x4*)&aLds[(r + 16) * 256 + (((c0 + 1) ^ key) << 2)];
            bf16x8 a0, a1;
#pragma unroll
            for (int j = 0; j < 4; ++j) {
                a0[j]     = cvt1(a0lo[j]);
                a0[j + 4] = cvt1(a0hi[j]);
                a1[j]     = cvt1(a1lo[j]);
                a1[j + 4] = cvt1(a1hi[j]);
            }
            bf16x8 b0, b1, b2, b3;
#pragma unroll
            for (int j = 0; j < 8; ++j) {
                const size_t krow = (size_t)(k0 + g * 8 + j) * H_;
                b0[j] = cvt1(Wf[krow + nbase +  0 + r]);
                b1[j] = cvt1(Wf[krow + nbase + 16 + r]);
                b2[j] = cvt1(Wf[krow + nbase + 32 + r]);
                b3[j] = cvt1(Wf[krow + nbase + 48 + r]);
            }
            acc[0][0] = __builtin_amdgcn_mfma_f32_16x16x32_bf16(a0, b0, acc[0][0], 0, 0, 0);
            acc[0][1] = __builtin_amdgcn_mfma_f32_16x16x32_bf16(a0, b1, acc[0][1], 0, 0, 0);
            acc[0][2] = __builtin_amdgcn_mfma_f32_16x16x32_bf16(a0, b2, acc[0][2], 0, 0, 0);
            acc[0][3] = __builtin_amdgcn_mfma_f32_16x16x32_bf16(a0, b3, acc[0][3], 0, 0, 0);
            acc[1][0] = __builtin_amdgcn_mfma_f32_16x16x32_bf16(a1, b0, acc[1][0], 0, 0, 0);
            acc[1][1] = __builtin_amdgcn_mfma_f32_16x16x32_bf16(a1, b1, acc[1][1], 0, 0, 0);
            acc[1][2] = __builtin_amdgcn_mfma_f32_16x16x32_bf16(a1, b2, acc[1][2], 0, 0, 0);
            acc[1][3] = __builtin_amdgcn_mfma_f32_16x16x32_bf16(a1, b3, acc[1][3], 0, 0, 0);
        }
    }

    const int row0 = g * 4;
#pragma unroll
    for (int mf = 0; mf < 2; ++mf) {
#pragma unroll
        for (int nf = 0; nf < 4; ++nf) {
            const int h = nbase + nf * 16 + r;
#pragma unroll
            for (int i = 0; i < 4; ++i) {
                const int bb = mf * 16 + row0 + i;
                out[((size_t)bb * L_ + l) * H_ + h] = acc[mf][nf][i];
            }
        }
    }
    if (l == L_ - 1) {
        float* out2 = out + (size_t)B_ * L_ * H_;
#pragma unroll
        for (int mf = 0; mf < 2; ++mf)
#pragma unroll
            for (int nf = 0; nf < 4; ++nf) {
                const int h = nbase + nf * 16 + r;
#pragma unroll
                for (int i = 0; i < 4; ++i) {
                    const int bb = mf * 16 + row0 + i;
                    out2[(size_t)bb * H_ + h] = acc[mf][nf][i];
                }
            }
    }
}

extern "C" void kernel_launch(void* const* d_in, const int* in_sizes, int n_in,
                              void* d_out, int out_size, void* d_ws, size_t ws_size,
                              hipStream_t stream) {
    const float* word_rep = (const float*)d_in[0];
    const float* cnn      = (const float*)d_in[1];
    float* out = (float*)d_out;

    const size_t wt_bytes = (size_t)MAXSTEP * E_ * H_ * sizeof(short);
    if (ws_size >= wt_bytes) {
        short* wt = (short*)d_ws;
        transpose_w_kernel<<<dim3(8, 8, 20), dim3(32, 8), 0, stream>>>(cnn, wt);
        vaw_mfma_kernel<true><<<dim3(L_), dim3(256), 0, stream>>>(word_rep, wt, out);
    } else {
        vaw_mfma_kernel<false><<<dim3(L_), dim3(256), 0, stream>>>(word_rep, cnn, out);
    }
}

// Round 5
// 54.531 us; speedup vs baseline: 1.3618x; 1.1013x over previous
//
#include <hip/hip_runtime.h>
#include <hip/hip_bf16.h>

#define B_ 32
#define L_ 2048
#define E_ 256
#define H_ 256
#define MAXSTEP 20
#define NL 4   // l-tiles per block

typedef __attribute__((ext_vector_type(4))) float f32x4;
typedef __attribute__((ext_vector_type(8))) short bf16x8;
using bf16 = __hip_bfloat16;

__device__ inline short cvt1(float x) {
    bf16 b = __float2bfloat16(x);
    return *reinterpret_cast<short*>(&b);
}

// Transpose + convert: cnn fp32 [s][e][h] -> wt bf16 [s][h][e] (K-contiguous B operand).
__global__ void transpose_w_kernel(const float* __restrict__ cnn, short* __restrict__ wt) {
    __shared__ short tile[32][33];
    const int s  = blockIdx.z;
    const int e0 = blockIdx.y * 32;
    const int h0 = blockIdx.x * 32;
    const int tx = threadIdx.x;
    const int ty = threadIdx.y;
    const float* src = cnn + ((size_t)s * E_ + e0) * H_ + h0;
#pragma unroll
    for (int i = ty; i < 32; i += 8)
        tile[i][tx] = cvt1(src[(size_t)i * H_ + tx]);
    __syncthreads();
    short* dst = wt + ((size_t)s * H_ + h0) * E_ + e0;
#pragma unroll
    for (int i = ty; i < 32; i += 8)
        dst[(size_t)i * E_ + tx] = tile[tx][i];
}

// Block p handles l = 4p..4p+3. Per tile: A (32x256 fp32, 32 KB) async-staged via
// global_load_lds into alternating LDS buffers; counted vmcnt(8) keeps the next
// tile's 8 loads in flight across barriers (never drain to 0 mid-loop).
// 4 waves; wave w: rows b=0..31, cols h in [w*64, w*64+64).
// mfma_f32_16x16x32_bf16: A row = lane&15, k=(lane>>4)*8+j; B col = lane&15;
// C/D col = lane&15, row = (lane>>4)*4 + reg.
template <bool TRANS>
__global__ __launch_bounds__(256) void vaw_mfma_kernel(
        const float* __restrict__ A, const void* __restrict__ W, float* __restrict__ out) {
    __shared__ __align__(16) float aLds[2][B_ * E_];   // 2 x 32 KB

    const int l0   = blockIdx.x * NL;
    const int wv   = threadIdx.x >> 6;
    const int lane = threadIdx.x & 63;
    const int r    = lane & 15;
    const int g    = lane >> 4;
    const int nbase = wv * 64;
    const int key   = r & 7;          // (r+16)&7 == r&7

    // Stage tile `it` into buffer it&1. Source XOR-swizzled per 16B chunk; LDS
    // dest linear (wave-uniform base + lane*16, required by global_load_lds).
    auto stage = [&](int it) {
        float* dst = aLds[it & 1];
        const int l = l0 + it;
#pragma unroll
        for (int t = 0; t < 8; ++t) {
            const int b  = t * 4 + wv;
            const int cg = lane ^ (b & 7);
            const float* gp = A + ((size_t)b * L_ + l) * E_ + cg * 4;
            __builtin_amdgcn_global_load_lds(
                (const __attribute__((address_space(1))) void*)gp,
                (__attribute__((address_space(3))) void*)&dst[b * 256],
                16, 0, 0);
        }
    };

    stage(0);   // prologue

#pragma unroll 1
    for (int it = 0; it < NL; ++it) {
        const int l   = l0 + it;
        const int s   = l % MAXSTEP;
        const int cur = it & 1;

        if (it < NL - 1) {
            stage(it + 1);                                   // next tile in flight
            asm volatile("s_waitcnt vmcnt(8)" ::: "memory"); // current tile landed
        } else {
            asm volatile("s_waitcnt vmcnt(0)" ::: "memory");
        }
        __builtin_amdgcn_s_barrier();        // all waves' stage(it) complete
        __builtin_amdgcn_sched_barrier(0);

        f32x4 acc[2][4] = {};

        if constexpr (TRANS) {
            const short* wtb = (const short*)W + ((size_t)s * H_ + nbase + r) * E_ + g * 8;
            bf16x8 bbuf[2][4];
#pragma unroll
            for (int nf = 0; nf < 4; ++nf)
                bbuf[0][nf] = *(const bf16x8*)(wtb + (size_t)nf * 16 * E_);
#pragma unroll
            for (int kk = 0; kk < 8; ++kk) {
                if (kk < 7) {
#pragma unroll
                    for (int nf = 0; nf < 4; ++nf)
                        bbuf[(kk + 1) & 1][nf] =
                            *(const bf16x8*)(wtb + (size_t)nf * 16 * E_ + (kk + 1) * 32);
                }
                const int c0 = kk * 8 + g * 2;
                f32x4 a0lo = *(const f32x4*)&aLds[cur][r * 256 + ((c0 ^ key) << 2)];
                f32x4 a0hi = *(const f32x4*)&aLds[cur][r * 256 + (((c0 + 1) ^ key) << 2)];
                f32x4 a1lo = *(const f32x4*)&aLds[cur][(r + 16) * 256 + ((c0 ^ key) << 2)];
                f32x4 a1hi = *(const f32x4*)&aLds[cur][(r + 16) * 256 + (((c0 + 1) ^ key) << 2)];
                bf16x8 a0, a1;
#pragma unroll
                for (int j = 0; j < 4; ++j) {
                    a0[j]     = cvt1(a0lo[j]);
                    a0[j + 4] = cvt1(a0hi[j]);
                    a1[j]     = cvt1(a1lo[j]);
                    a1[j + 4] = cvt1(a1hi[j]);
                }
#pragma unroll
                for (int nf = 0; nf < 4; ++nf) {
                    acc[0][nf] = __builtin_amdgcn_mfma_f32_16x16x32_bf16(a0, bbuf[kk & 1][nf], acc[0][nf], 0, 0, 0);
                    acc[1][nf] = __builtin_amdgcn_mfma_f32_16x16x32_bf16(a1, bbuf[kk & 1][nf], acc[1][nf], 0, 0, 0);
                }
            }
        } else {
            const float* Wf = (const float*)W + (size_t)s * E_ * H_;
#pragma unroll 2
            for (int kk = 0; kk < 8; ++kk) {
                const int k0 = kk * 32;
                const int c0 = kk * 8 + g * 2;
                f32x4 a0lo = *(const f32x4*)&aLds[cur][r * 256 + ((c0 ^ key) << 2)];
                f32x4 a0hi = *(const f32x4*)&aLds[cur][r * 256 + (((c0 + 1) ^ key) << 2)];
                f32x4 a1lo = *(const f32x4*)&aLds[cur][(r + 16) * 256 + ((c0 ^ key) << 2)];
                f32x4 a1hi = *(const f32x4*)&aLds[cur][(r + 16) * 256 + (((c0 + 1) ^ key) << 2)];
                bf16x8 a0, a1;
#pragma unroll
                for (int j = 0; j < 4; ++j) {
                    a0[j]     = cvt1(a0lo[j]);
                    a0[j + 4] = cvt1(a0hi[j]);
                    a1[j]     = cvt1(a1lo[j]);
                    a1[j + 4] = cvt1(a1hi[j]);
                }
                bf16x8 b0, b1, b2, b3;
#pragma unroll
                for (int j = 0; j < 8; ++j) {
                    const size_t krow = (size_t)(k0 + g * 8 + j) * H_;
                    b0[j] = cvt1(Wf[krow + nbase +  0 + r]);
                    b1[j] = cvt1(Wf[krow + nbase + 16 + r]);
                    b2[j] = cvt1(Wf[krow + nbase + 32 + r]);
                    b3[j] = cvt1(Wf[krow + nbase + 48 + r]);
                }
                acc[0][0] = __builtin_amdgcn_mfma_f32_16x16x32_bf16(a0, b0, acc[0][0], 0, 0, 0);
                acc[0][1] = __builtin_amdgcn_mfma_f32_16x16x32_bf16(a0, b1, acc[0][1], 0, 0, 0);
                acc[0][2] = __builtin_amdgcn_mfma_f32_16x16x32_bf16(a0, b2, acc[0][2], 0, 0, 0);
                acc[0][3] = __builtin_amdgcn_mfma_f32_16x16x32_bf16(a0, b3, acc[0][3], 0, 0, 0);
                acc[1][0] = __builtin_amdgcn_mfma_f32_16x16x32_bf16(a1, b0, acc[1][0], 0, 0, 0);
                acc[1][1] = __builtin_amdgcn_mfma_f32_16x16x32_bf16(a1, b1, acc[1][1], 0, 0, 0);
                acc[1][2] = __builtin_amdgcn_mfma_f32_16x16x32_bf16(a1, b2, acc[1][2], 0, 0, 0);
                acc[1][3] = __builtin_amdgcn_mfma_f32_16x16x32_bf16(a1, b3, acc[1][3], 0, 0, 0);
            }
        }

        const int row0 = g * 4;
#pragma unroll
        for (int mf = 0; mf < 2; ++mf) {
#pragma unroll
            for (int nf = 0; nf < 4; ++nf) {
                const int h = nbase + nf * 16 + r;
#pragma unroll
                for (int i = 0; i < 4; ++i) {
                    const int bb = mf * 16 + row0 + i;
                    out[((size_t)bb * L_ + l) * H_ + h] = acc[mf][nf][i];
                }
            }
        }
        if (l == L_ - 1) {
            float* out2 = out + (size_t)B_ * L_ * H_;
#pragma unroll
            for (int mf = 0; mf < 2; ++mf)
#pragma unroll
                for (int nf = 0; nf < 4; ++nf) {
                    const int h = nbase + nf * 16 + r;
#pragma unroll
                    for (int i = 0; i < 4; ++i) {
                        const int bb = mf * 16 + row0 + i;
                        out2[(size_t)bb * H_ + h] = acc[mf][nf][i];
                    }
                }
        }

        __builtin_amdgcn_s_barrier();   // all reads of buf[cur] done before overwrite
    }
}

extern "C" void kernel_launch(void* const* d_in, const int* in_sizes, int n_in,
                              void* d_out, int out_size, void* d_ws, size_t ws_size,
                              hipStream_t stream) {
    const float* word_rep = (const float*)d_in[0];
    const float* cnn      = (const float*)d_in[1];
    float* out = (float*)d_out;

    const size_t wt_bytes = (size_t)MAXSTEP * E_ * H_ * sizeof(short);
    if (ws_size >= wt_bytes) {
        short* wt = (short*)d_ws;
        transpose_w_kernel<<<dim3(8, 8, 20), dim3(32, 8), 0, stream>>>(cnn, wt);
        vaw_mfma_kernel<true><<<dim3(L_ / NL), dim3(256), 0, stream>>>(word_rep, wt, out);
    } else {
        vaw_mfma_kernel<false><<<dim3(L_ / NL), dim3(256), 0, stream>>>(word_rep, cnn, out);
    }
}

// Round 6
// 45.034 us; speedup vs baseline: 1.6489x; 1.2109x over previous
//
#include <hip/hip_runtime.h>
#include <hip/hip_bf16.h>

#define B_ 32
#define L_ 2048
#define E_ 256
#define H_ 256
#define MAXSTEP 20
#define NL 4      // l-tiles per block
#define NCHUNK 26 // ceil(103/NL)

typedef __attribute__((ext_vector_type(4))) float f32x4;
typedef __attribute__((ext_vector_type(8))) short bf16x8;
using bf16 = __hip_bfloat16;

__device__ inline short cvt1(float x) {
    bf16 b = __float2bfloat16(x);
    return *reinterpret_cast<short*>(&b);
}

// Transpose + convert: cnn fp32 [s][e][h] -> wt bf16 [s][h][e] (K-contiguous B operand).
__global__ void transpose_w_kernel(const float* __restrict__ cnn, short* __restrict__ wt) {
    __shared__ short tile[32][33];
    const int s  = blockIdx.z;
    const int e0 = blockIdx.y * 32;
    const int h0 = blockIdx.x * 32;
    const int tx = threadIdx.x;
    const int ty = threadIdx.y;
    const float* src = cnn + ((size_t)s * E_ + e0) * H_ + h0;
#pragma unroll
    for (int i = ty; i < 32; i += 8)
        tile[i][tx] = cvt1(src[(size_t)i * H_ + tx]);
    __syncthreads();
    short* dst = wt + ((size_t)s * H_ + h0) * E_ + e0;
#pragma unroll
    for (int i = ty; i < 32; i += 8)
        dst[(size_t)i * E_ + tx] = tile[tx][i];
}

// Same-s blocking: block = (s, chunk); handles l = s + 20*(chunk*NL + it), it=0..3
// (clamped at the s-class tail; duplicated iterations recompute/rewrite identical
// values — benign). B (W^T[s], this wave's 64 h-rows) is loaded ONCE into 128
// VGPRs, so the per-iteration vmem stream is ONLY stage(8)+stores(32): the
// counted vmcnt(40) retires exactly the current A-tile and never waits on
// stores. A: 32x256 fp32 (32 KB) double-buffered via global_load_lds, source
// XOR-swizzled per 16B chunk (LDS dest linear), same XOR on ds_read side.
// mfma_f32_16x16x32_bf16: A row = lane&15, k=(lane>>4)*8+j; B col = lane&15;
// C/D col = lane&15, row = (lane>>4)*4 + reg.
__global__ __launch_bounds__(256, 2) void vaw_sames_kernel(
        const float* __restrict__ A, const short* __restrict__ Wt,
        float* __restrict__ out) {
    __shared__ __align__(16) float aLds[2][B_ * E_];   // 2 x 32 KB

    const int s     = blockIdx.x / NCHUNK;
    const int chunk = blockIdx.x % NCHUNK;
    const int cnt   = (s < 8) ? 103 : 102;   // #{l < 2048 : l % 20 == s}
    const int wv    = threadIdx.x >> 6;
    const int lane  = threadIdx.x & 63;
    const int r     = lane & 15;
    const int g     = lane >> 4;
    const int nbase = wv * 64;
    const int key   = r & 7;

    // ---- B into registers: breg[kk][nf], 32 x 16B loads from L2-resident Wt.
    const short* wtb = Wt + ((size_t)s * H_ + nbase + r) * E_ + g * 8;
    bf16x8 breg[8][4];
#pragma unroll
    for (int kk = 0; kk < 8; ++kk)
#pragma unroll
        for (int nf = 0; nf < 4; ++nf)
            breg[kk][nf] = *(const bf16x8*)(wtb + (size_t)nf * 16 * E_ + kk * 32);

    auto lof = [&](int it) {
        int idx = chunk * NL + it;
        if (idx > cnt - 1) idx = cnt - 1;
        return s + 20 * idx;
    };

    auto stage = [&](int it) {
        const int l = lof(it);
        float* dst = aLds[it & 1];
#pragma unroll
        for (int t = 0; t < 8; ++t) {
            const int b  = t * 4 + wv;
            const int cg = lane ^ (b & 7);
            const float* gp = A + ((size_t)b * L_ + l) * E_ + cg * 4;
            __builtin_amdgcn_global_load_lds(
                (const __attribute__((address_space(1))) void*)gp,
                (__attribute__((address_space(3))) void*)&dst[b * 256],
                16, 0, 0);
        }
    };

    stage(0);   // prologue

#pragma unroll
    for (int it = 0; it < NL; ++it) {
        const int l   = lof(it);
        const int cur = it & 1;

        if (it < NL - 1) stage(it + 1);
        // In-order vmcnt queue at this point:
        //   it==0:  [breg(32) | stage0(8) | stage1(8)]          -> wait 8
        //   0<it<3: [stage(it)(8) | stores(it-1)(32) | stage(it+1)(8)] -> wait 40
        //   it==3:  [stage3(8) | stores2(32)]                   -> wait 32
        if (it == 0)           asm volatile("s_waitcnt vmcnt(8)"  ::: "memory");
        else if (it < NL - 1)  asm volatile("s_waitcnt vmcnt(40)" ::: "memory");
        else                   asm volatile("s_waitcnt vmcnt(32)" ::: "memory");
        __builtin_amdgcn_s_barrier();        // all waves' stage(it) complete
        __builtin_amdgcn_sched_barrier(0);

        f32x4 acc[2][4] = {};
#pragma unroll
        for (int kk = 0; kk < 8; ++kk) {
            const int c0 = kk * 8 + g * 2;
            f32x4 a0lo = *(const f32x4*)&aLds[cur][r * 256 + ((c0 ^ key) << 2)];
            f32x4 a0hi = *(const f32x4*)&aLds[cur][r * 256 + (((c0 + 1) ^ key) << 2)];
            f32x4 a1lo = *(const f32x4*)&aLds[cur][(r + 16) * 256 + ((c0 ^ key) << 2)];
            f32x4 a1hi = *(const f32x4*)&aLds[cur][(r + 16) * 256 + (((c0 + 1) ^ key) << 2)];
            bf16x8 a0, a1;
#pragma unroll
            for (int j = 0; j < 4; ++j) {
                a0[j]     = cvt1(a0lo[j]);
                a0[j + 4] = cvt1(a0hi[j]);
                a1[j]     = cvt1(a1lo[j]);
                a1[j + 4] = cvt1(a1hi[j]);
            }
#pragma unroll
            for (int nf = 0; nf < 4; ++nf) {
                acc[0][nf] = __builtin_amdgcn_mfma_f32_16x16x32_bf16(a0, breg[kk][nf], acc[0][nf], 0, 0, 0);
                acc[1][nf] = __builtin_amdgcn_mfma_f32_16x16x32_bf16(a1, breg[kk][nf], acc[1][nf], 0, 0, 0);
            }
        }

        const int row0 = g * 4;
#pragma unroll
        for (int mf = 0; mf < 2; ++mf) {
#pragma unroll
            for (int nf = 0; nf < 4; ++nf) {
                const int h = nbase + nf * 16 + r;
#pragma unroll
                for (int i = 0; i < 4; ++i) {
                    const int bb = mf * 16 + row0 + i;
                    out[((size_t)bb * L_ + l) * H_ + h] = acc[mf][nf][i];
                }
            }
        }
        if (l == L_ - 1) {
            float* out2 = out + (size_t)B_ * L_ * H_;
#pragma unroll
            for (int mf = 0; mf < 2; ++mf)
#pragma unroll
                for (int nf = 0; nf < 4; ++nf) {
                    const int h = nbase + nf * 16 + r;
#pragma unroll
                    for (int i = 0; i < 4; ++i) {
                        const int bb = mf * 16 + row0 + i;
                        out2[(size_t)bb * H_ + h] = acc[mf][nf][i];
                    }
                }
        }

        __builtin_amdgcn_s_barrier();   // reads of buf[cur] done before overwrite
    }
}

// Fallback (no workspace): round-5 structure, B from fp32 cnn per k-step.
__global__ __launch_bounds__(256) void vaw_fallback_kernel(
        const float* __restrict__ A, const float* __restrict__ W, float* __restrict__ out) {
    __shared__ __align__(16) float aLds[2][B_ * E_];
    const int l0   = blockIdx.x * NL;
    const int wv   = threadIdx.x >> 6;
    const int lane = threadIdx.x & 63;
    const int r    = lane & 15;
    const int g    = lane >> 4;
    const int nbase = wv * 64;
    const int key   = r & 7;

    auto stage = [&](int it) {
        float* dst = aLds[it & 1];
        const int l = l0 + it;
#pragma unroll
        for (int t = 0; t < 8; ++t) {
            const int b  = t * 4 + wv;
            const int cg = lane ^ (b & 7);
            const float* gp = A + ((size_t)b * L_ + l) * E_ + cg * 4;
            __builtin_amdgcn_global_load_lds(
                (const __attribute__((address_space(1))) void*)gp,
                (__attribute__((address_space(3))) void*)&dst[b * 256],
                16, 0, 0);
        }
    };

    stage(0);
#pragma unroll 1
    for (int it = 0; it < NL; ++it) {
        const int l   = l0 + it;
        const int sidx = l % MAXSTEP;
        const int cur = it & 1;
        if (it < NL - 1) {
            stage(it + 1);
            asm volatile("s_waitcnt vmcnt(8)" ::: "memory");
        } else {
            asm volatile("s_waitcnt vmcnt(0)" ::: "memory");
        }
        __builtin_amdgcn_s_barrier();
        __builtin_amdgcn_sched_barrier(0);

        f32x4 acc[2][4] = {};
        const float* Wf = W + (size_t)sidx * E_ * H_;
#pragma unroll 2
        for (int kk = 0; kk < 8; ++kk) {
            const int k0 = kk * 32;
            const int c0 = kk * 8 + g * 2;
            f32x4 a0lo = *(const f32x4*)&aLds[cur][r * 256 + ((c0 ^ key) << 2)];
            f32x4 a0hi = *(const f32x4*)&aLds[cur][r * 256 + (((c0 + 1) ^ key) << 2)];
            f32x4 a1lo = *(const f32x4*)&aLds[cur][(r + 16) * 256 + ((c0 ^ key) << 2)];
            f32x4 a1hi = *(const f32x4*)&aLds[cur][(r + 16) * 256 + (((c0 + 1) ^ key) << 2)];
            bf16x8 a0, a1;
#pragma unroll
            for (int j = 0; j < 4; ++j) {
                a0[j]     = cvt1(a0lo[j]);
                a0[j + 4] = cvt1(a0hi[j]);
                a1[j]     = cvt1(a1lo[j]);
                a1[j + 4] = cvt1(a1hi[j]);
            }
            bf16x8 b0, b1, b2, b3;
#pragma unroll
            for (int j = 0; j < 8; ++j) {
                const size_t krow = (size_t)(k0 + g * 8 + j) * H_;
                b0[j] = cvt1(Wf[krow + nbase +  0 + r]);
                b1[j] = cvt1(Wf[krow + nbase + 16 + r]);
                b2[j] = cvt1(Wf[krow + nbase + 32 + r]);
                b3[j] = cvt1(Wf[krow + nbase + 48 + r]);
            }
            acc[0][0] = __builtin_amdgcn_mfma_f32_16x16x32_bf16(a0, b0, acc[0][0], 0, 0, 0);
            acc[0][1] = __builtin_amdgcn_mfma_f32_16x16x32_bf16(a0, b1, acc[0][1], 0, 0, 0);
            acc[0][2] = __builtin_amdgcn_mfma_f32_16x16x32_bf16(a0, b2, acc[0][2], 0, 0, 0);
            acc[0][3] = __builtin_amdgcn_mfma_f32_16x16x32_bf16(a0, b3, acc[0][3], 0, 0, 0);
            acc[1][0] = __builtin_amdgcn_mfma_f32_16x16x32_bf16(a1, b0, acc[1][0], 0, 0, 0);
            acc[1][1] = __builtin_amdgcn_mfma_f32_16x16x32_bf16(a1, b1, acc[1][1], 0, 0, 0);
            acc[1][2] = __builtin_amdgcn_mfma_f32_16x16x32_bf16(a1, b2, acc[1][2], 0, 0, 0);
            acc[1][3] = __builtin_amdgcn_mfma_f32_16x16x32_bf16(a1, b3, acc[1][3], 0, 0, 0);
        }

        const int row0 = g * 4;
#pragma unroll
        for (int mf = 0; mf < 2; ++mf)
#pragma unroll
            for (int nf = 0; nf < 4; ++nf) {
                const int h = nbase + nf * 16 + r;
#pragma unroll
                for (int i = 0; i < 4; ++i) {
                    const int bb = mf * 16 + row0 + i;
                    out[((size_t)bb * L_ + l) * H_ + h] = acc[mf][nf][i];
                }
            }
        if (l == L_ - 1) {
            float* out2 = out + (size_t)B_ * L_ * H_;
#pragma unroll
            for (int mf = 0; mf < 2; ++mf)
#pragma unroll
                for (int nf = 0; nf < 4; ++nf) {
                    const int h = nbase + nf * 16 + r;
#pragma unroll
                    for (int i = 0; i < 4; ++i) {
                        const int bb = mf * 16 + row0 + i;
                        out2[(size_t)bb * H_ + h] = acc[mf][nf][i];
                    }
                }
        }
        __builtin_amdgcn_s_barrier();
    }
}

extern "C" void kernel_launch(void* const* d_in, const int* in_sizes, int n_in,
                              void* d_out, int out_size, void* d_ws, size_t ws_size,
                              hipStream_t stream) {
    const float* word_rep = (const float*)d_in[0];
    const float* cnn      = (const float*)d_in[1];
    float* out = (float*)d_out;

    const size_t wt_bytes = (size_t)MAXSTEP * E_ * H_ * sizeof(short);
    if (ws_size >= wt_bytes) {
        short* wt = (short*)d_ws;
        transpose_w_kernel<<<dim3(8, 8, 20), dim3(32, 8), 0, stream>>>(cnn, wt);
        vaw_sames_kernel<<<dim3(MAXSTEP * NCHUNK), dim3(256), 0, stream>>>(word_rep, wt, out);
    } else {
        vaw_fallback_kernel<<<dim3(L_ / NL), dim3(256), 0, stream>>>(word_rep, cnn, out);
    }
}